// Round 6
// baseline (155.109 us; speedup 1.0000x reference)
//
#include <hip/hip_runtime.h>
#include <math.h>

// Problem constants (match reference)
#define MB 8      // batch
#define MM 384    // checks
#define NN 1536   // variables
#define LL 20     // layers
#define RW 8      // row weight of H
#define HE 4      // edges per thread (half row)
#define NE (MM*RW)  // 3072 edges
#define NT 768    // bp block size (2 threads per check row)
#define VP 12     // max column degree supported (validated: never hit)
#define VG 3      // VP/4 float4 groups

#define LOG2E 1.44269504f
#define LN2   0.69314718f

// Soft barrier: LDS visibility only (s_waitcnt lgkmcnt(0) + s_barrier).
// Deliberately does NOT drain vmcnt — global prefetches stay in flight.
#define SOFT_BAR() asm volatile("s_waitcnt lgkmcnt(0)\n\ts_barrier" ::: "memory")

// Lane xor-1 exchange via DPP quad_perm(1,0,3,2): pure VALU.
static __device__ __forceinline__ float dpp_xor1(float x) {
    return __int_as_float(
        __builtin_amdgcn_mov_dpp(__float_as_int(x), 0xB1, 0xF, 0xF, true));
}

// ---------------------------------------------------------------------------
// Fused setup: one block (256 thr = 4 waves) per check row (unchanged R5:
// swizzled slot positions, log2-domain base, ln2-scaled marg weights).
// ---------------------------------------------------------------------------
__global__ __launch_bounds__(256) void setup_kernel(
    const float* __restrict__ H,
    const float* __restrict__ llrs,
    const float* __restrict__ w_llr,
    const float* __restrict__ w_de,
    const float* __restrict__ marg_de,
    int*   __restrict__ col_pack,
    float* __restrict__ base_e,
    float* __restrict__ wde_vT,
    float* __restrict__ marg_vT,
    int*   __restrict__ gcnt,
    float* __restrict__ out) {
    const int m = blockIdx.x;
    const int t = threadIdx.x;
    const int w = t >> 6, lane = t & 63;
    __shared__ int s_qcol[4][RW];
    __shared__ int s_qcnt[4];
    __shared__ int s_col[RW];
    __shared__ int s_pos[RW];

    const float* row = H + (size_t)m * NN;
    int count = 0;
    for (int c0 = w * 384; c0 < (w + 1) * 384; c0 += 64) {
        float v = row[c0 + lane];
        unsigned long long mask = __ballot(v != 0.0f);
        if (v != 0.0f) {
            int pos = count + (int)__popcll(mask & ((1ull << lane) - 1ull));
            if (pos < RW) s_qcol[w][pos] = c0 + lane;
        }
        count += (int)__popcll(mask);
    }
    if (lane == 0) s_qcnt[w] = (count < RW) ? count : RW;
    __syncthreads();
    if (t == 0) {
        int off = 0;
        for (int q = 0; q < 4; ++q)
            for (int i = 0; i < s_qcnt[q]; ++i) {
                if (off < RW) s_col[off] = s_qcol[q][i];
                ++off;
            }
    }
    __syncthreads();

    if (t < RW) {
        int c = s_col[t];
        int pos = atomicAdd(&gcnt[c], 1);
        if (pos >= VP) pos = VP - 1;   // clamp (validated: never hit)
        // bank-conflict swizzle of the intra-group position
        int ps = (pos & ~3) | ((pos & 3) ^ ((c >> 3) & 3));
        s_pos[t] = ps;
        col_pack[m * RW + t] = c | (ps << 16);
        // messages live in log2 domain -> marg weight carries ln2
        marg_vT[((ps >> 2) * NN + c) * 4 + (ps & 3)] = marg_de[m * NN + c] * LN2;
    }
    if (m == 0 && t == 0) out[0] = 0.0f;
    __syncthreads();

    for (int idx = t; idx < LL * RW; idx += 256) {
        int l = idx >> 3;
        int k = idx & 7;
        int c = s_col[k];
        int ps = s_pos[k];
        wde_vT[((l * VG + (ps >> 2)) * NN + c) * 4 + (ps & 3)] =
            w_de[(size_t)l * MM * NN + (size_t)m * NN + c];
        // base in log2 domain
        base_e[l * NE + m * RW + k] = llrs[c] * w_llr[l * NN + c] * LOG2E;
    }
}

// ===========================================================================
// One full layer body, TWO independent batches per block (gap-filling ILP).
// Weight/graph registers are batch-shared; per-batch state duplicates.
// Check update uses the exact identity 2*atanh(P/d) = log((d+P)/(d-P))
// (P = full row product) -- no exclusion products needed.
// ===========================================================================
#define LAYER_BODY(lv, WC0, WC1, WN0, WN1, BN)                                \
{                                                                             \
    /* prefetch next layer's shared weight streams (stay in flight) */        \
    {                                                                         \
        int lb = ((lv) + 1 < LL) ? ((lv) + 1) : (LL - 1);                     \
        _Pragma("unroll")                                                     \
        for (int jg = 0; jg < VG; ++jg) {                                     \
            float4 a = ((const float4*)wde_vT)[(lb * VG + jg) * NN + t];      \
            WN0[jg*4+0]=a.x; WN0[jg*4+1]=a.y; WN0[jg*4+2]=a.z; WN0[jg*4+3]=a.w; \
            float4 c4 = ((const float4*)wde_vT)[(lb * VG + jg) * NN + t + NT];\
            WN1[jg*4+0]=c4.x; WN1[jg*4+1]=c4.y; WN1[jg*4+2]=c4.z; WN1[jg*4+3]=c4.w; \
        }                                                                     \
        const float4 bp4 = ((const float4*)(base_e_g + lb * NE))[t];          \
        BN[0]=bp4.x; BN[1]=bp4.y; BN[2]=bp4.z; BN[3]=bp4.w;                   \
    }                                                                         \
    /* phase A: owner gather for BOTH batches: S + full beliefs (lv-1) */     \
    float bel00, bel01, bel10, bel11;                                         \
    {                                                                         \
        float4 xa0 = ((const float4*)s_cN0)[t];                               \
        float4 xb0 = ((const float4*)s_cN0)[t + NT];                          \
        float4 xa1 = ((const float4*)s_cN1)[t];                               \
        float4 xb1 = ((const float4*)s_cN1)[t + NT];                          \
        float S00 = xa0.x*WC0[0] + xa0.y*WC0[1] + xa0.z*WC0[2] + xa0.w*WC0[3]; \
        float S01 = xb0.x*WC1[0] + xb0.y*WC1[1] + xb0.z*WC1[2] + xb0.w*WC1[3]; \
        float S10 = xa1.x*WC0[0] + xa1.y*WC0[1] + xa1.z*WC0[2] + xa1.w*WC0[3]; \
        float S11 = xb1.x*WC1[0] + xb1.y*WC1[1] + xb1.z*WC1[2] + xb1.w*WC1[3]; \
        bel00 = bias[0] + xa0.x*mg0[0] + xa0.y*mg0[1] + xa0.z*mg0[2] + xa0.w*mg0[3]; \
        bel01 = bias[1] + xb0.x*mg1[0] + xb0.y*mg1[1] + xb0.z*mg1[2] + xb0.w*mg1[3]; \
        bel10 = bias[0] + xa1.x*mg0[0] + xa1.y*mg0[1] + xa1.z*mg0[2] + xa1.w*mg0[3]; \
        bel11 = bias[1] + xb1.x*mg1[0] + xb1.y*mg1[1] + xb1.z*mg1[2] + xb1.w*mg1[3]; \
        if (deg0 > 4) {                                                       \
            float4 a = ((const float4*)s_cN0)[NN + t];                        \
            float4 c4 = ((const float4*)s_cN1)[NN + t];                       \
            S00   += a.x*WC0[4] + a.y*WC0[5] + a.z*WC0[6] + a.w*WC0[7];       \
            bel00 += a.x*mg0[4] + a.y*mg0[5] + a.z*mg0[6] + a.w*mg0[7];       \
            S10   += c4.x*WC0[4] + c4.y*WC0[5] + c4.z*WC0[6] + c4.w*WC0[7];   \
            bel10 += c4.x*mg0[4] + c4.y*mg0[5] + c4.z*mg0[6] + c4.w*mg0[7];   \
        }                                                                     \
        if (deg1 > 4) {                                                       \
            float4 a = ((const float4*)s_cN0)[NN + t + NT];                   \
            float4 c4 = ((const float4*)s_cN1)[NN + t + NT];                  \
            S01   += a.x*WC1[4] + a.y*WC1[5] + a.z*WC1[6] + a.w*WC1[7];       \
            bel01 += a.x*mg1[4] + a.y*mg1[5] + a.z*mg1[6] + a.w*mg1[7];       \
            S11   += c4.x*WC1[4] + c4.y*WC1[5] + c4.z*WC1[6] + c4.w*WC1[7];   \
            bel11 += c4.x*mg1[4] + c4.y*mg1[5] + c4.z*mg1[6] + c4.w*mg1[7];   \
        }                                                                     \
        if (deg0 > 8) {                                                       \
            float4 a = ((const float4*)s_cN0)[2 * NN + t];                    \
            float4 c4 = ((const float4*)s_cN1)[2 * NN + t];                   \
            S00   += a.x*WC0[8] + a.y*WC0[9] + a.z*WC0[10] + a.w*WC0[11];     \
            bel00 += a.x*mg0[8] + a.y*mg0[9] + a.z*mg0[10] + a.w*mg0[11];     \
            S10   += c4.x*WC0[8] + c4.y*WC0[9] + c4.z*WC0[10] + c4.w*WC0[11]; \
            bel10 += c4.x*mg0[8] + c4.y*mg0[9] + c4.z*mg0[10] + c4.w*mg0[11]; \
        }                                                                     \
        if (deg1 > 8) {                                                       \
            float4 a = ((const float4*)s_cN0)[2 * NN + t + NT];               \
            float4 c4 = ((const float4*)s_cN1)[2 * NN + t + NT];              \
            S01   += a.x*WC1[8] + a.y*WC1[9] + a.z*WC1[10] + a.w*WC1[11];     \
            bel01 += a.x*mg1[8] + a.y*mg1[9] + a.z*mg1[10] + a.w*mg1[11];     \
            S11   += c4.x*WC1[8] + c4.y*WC1[9] + c4.z*WC1[10] + c4.w*WC1[11]; \
            bel11 += c4.x*mg1[8] + c4.y*mg1[9] + c4.z*mg1[10] + c4.w*mg1[11]; \
        }                                                                     \
        s_S0[t]      = S00;                                                   \
        s_S0[t + NT] = S01;                                                   \
        s_S1[t]      = S10;                                                   \
        s_S1[t + NT] = S11;                                                   \
    }                                                                         \
    SOFT_BAR();   /* barrier A: s_S visible; old s_cN consumed */             \
    {                                                                         \
        /* issue all scattered s_S reads first (both batches) */              \
        float ss0[HE], ss1[HE];                                               \
        _Pragma("unroll")                                                     \
        for (int k = 0; k < HE; ++k) ss0[k] = s_S0[col[k]];                   \
        _Pragma("unroll")                                                     \
        for (int k = 0; k < HE; ++k) ss1[k] = s_S1[col[k]];                   \
        /* filler: loss for layer lv-1, both batches */                       \
        if ((lv) > 0) {                                                       \
            const float rr = rhos[(lv) - 1];                                  \
            float sp00 = fmaxf(bel00, 0.0f) + __logf(1.0f + __expf(-fabsf(bel00))); \
            float sp01 = fmaxf(bel01, 0.0f) + __logf(1.0f + __expf(-fabsf(bel01))); \
            float sp10 = fmaxf(bel10, 0.0f) + __logf(1.0f + __expf(-fabsf(bel10))); \
            float sp11 = fmaxf(bel11, 0.0f) + __logf(1.0f + __expf(-fabsf(bel11))); \
            loss += rr * ((sp00 - omeg0[0] * bel00) + (sp01 - omeg0[1] * bel01) \
                        + (sp10 - omeg1[0] * bel10) + (sp11 - omeg1[1] * bel11)); \
        }                                                                     \
        const float rw_ = res_w[(lv)];                                        \
        float d0_[HE], d1_[HE];                                               \
        _Pragma("unroll")                                                     \
        for (int k = 0; k < HE; ++k) {                                        \
            float te = tm0[k] + ss0[k];               /* log2 domain */       \
            float e  = __builtin_amdgcn_exp2f(te);                            \
            float dd = 1.0f - 2.0f * __builtin_amdgcn_rcpf(e + 1.0f);         \
            dd = fminf(fmaxf(dd, -1.0f), 1.0f);                               \
            if (dd == 0.0f) dd = 1.0f;                                        \
            d0_[k] = dd;                                                      \
        }                                                                     \
        _Pragma("unroll")                                                     \
        for (int k = 0; k < HE; ++k) {                                        \
            float te = tm1[k] + ss1[k];                                       \
            float e  = __builtin_amdgcn_exp2f(te);                            \
            float dd = 1.0f - 2.0f * __builtin_amdgcn_rcpf(e + 1.0f);         \
            dd = fminf(fmaxf(dd, -1.0f), 1.0f);                               \
            if (dd == 0.0f) dd = 1.0f;                                        \
            d1_[k] = dd;                                                      \
        }                                                                     \
        float P0 = (d0_[0] * d0_[1]) * (d0_[2] * d0_[3]);                     \
        float P1 = (d1_[0] * d1_[1]) * (d1_[2] * d1_[3]);                     \
        P0 *= dpp_xor1(P0);   /* full 8-edge row product */                   \
        P1 *= dpp_xor1(P1);                                                   \
        _Pragma("unroll")                                                     \
        for (int k = 0; k < HE; ++k) {                                        \
            /* 2*atanh(P/d) = log((d+P)/(d-P)); |P|<=|d| so same sign */      \
            float la = __builtin_amdgcn_logf(fabsf(d0_[k] + P0));             \
            float lb2 = __builtin_amdgcn_logf(fabsf(d0_[k] - P0));            \
            float nm = sgn0 * (la - lb2) + rw_ * msg0[k];   /* log2 dom */    \
            msg0[k] = nm;                                                     \
            s_cN0[esl[k]] = nm;                                               \
        }                                                                     \
        _Pragma("unroll")                                                     \
        for (int k = 0; k < HE; ++k) {                                        \
            float la = __builtin_amdgcn_logf(fabsf(d1_[k] + P1));             \
            float lb2 = __builtin_amdgcn_logf(fabsf(d1_[k] - P1));            \
            float nm = sgn1 * (la - lb2) + rw_ * msg1[k];                     \
            msg1[k] = nm;                                                     \
            s_cN1[esl[k]] = nm;                                               \
        }                                                                     \
        /* prefold next layer's te base (off critical path) */                \
        _Pragma("unroll")                                                     \
        for (int k = 0; k < HE; ++k) { tm0[k] = BN[k] - msg0[k];              \
                                       tm1[k] = BN[k] - msg1[k]; }            \
    }                                                                         \
    SOFT_BAR();   /* barrier B: s_cN visible for next gather */               \
}

// ---------------------------------------------------------------------------
// Main BP kernel: 4 blocks, 768 threads, TWO batches per block.
// Zero atomics; swizzled CSC-padded LDS exchange; 2 SOFT barriers/layer;
// x2 unroll; degree-gated gather; DPP exchange; log2-domain messages;
// (d+P)/(d-P) self-exclusion.
// ---------------------------------------------------------------------------
__global__ __launch_bounds__(NT) void bp_kernel(
    const float* __restrict__ synd,       // (B,M,1)
    const float* __restrict__ errors,     // (B,N)
    const float* __restrict__ llrs,       // (N)
    const float* __restrict__ marg_llr,   // (N)
    const float* __restrict__ res_w,      // (L)
    const float* __restrict__ rhos,       // (L)
    const int*   __restrict__ col_pack,   // (E)  c | pos<<16 (swizzled pos)
    const float* __restrict__ base_e_g,   // (L,E)  log2-scaled
    const float* __restrict__ wde_vT,     // (L,VG,N,4)  swizzled elements
    const float* __restrict__ marg_vT,    // (VG,N,4)  ln2-scaled, swizzled
    const int*   __restrict__ gdeg,       // (N)  column degrees (= gcnt)
    float* __restrict__ out) {

    __shared__ float s_cN0[NN * VP];      // 72 KB  batch-0 edge messages
    __shared__ float s_cN1[NN * VP];      // 72 KB  batch-1 edge messages
    __shared__ float s_S0[NN];            // 6 KB
    __shared__ float s_S1[NN];            // 6 KB   (total 156.2 KB of 160)
    __shared__ float s_red[12];

    const int b0 = blockIdx.x;            // batches b0 and b0+4
    const int b1 = blockIdx.x + MB / 2;
    const int t = threadIdx.x;
    const int m = t >> 1;        // check row

    // ---- per-edge register state (graph shared across batches) ----
    int col[HE], esl[HE];
    {
        const int4 cp = ((const int4*)col_pack)[t];
        int v[HE] = {cp.x, cp.y, cp.z, cp.w};
        #pragma unroll
        for (int k = 0; k < HE; ++k) {
            int c = v[k] & 0xFFFF, pos = v[k] >> 16;
            col[k] = c;
            esl[k] = ((pos >> 2) * NN + c) * 4 + (pos & 3);
        }
    }
    float msg0[HE] = {0.0f, 0.0f, 0.0f, 0.0f};
    float msg1[HE] = {0.0f, 0.0f, 0.0f, 0.0f};
    const float sgn0 = 1.0f - 2.0f * synd[b0 * MM + m];
    const float sgn1 = 1.0f - 2.0f * synd[b1 * MM + m];

    // ---- owned-variable state ----
    const int deg0 = gdeg[t];
    const int deg1 = gdeg[t + NT];
    float bias[2], omeg0[2], omeg1[2];
    #pragma unroll
    for (int i = 0; i < 2; ++i) {
        int n = t + i * NT;
        bias[i] = llrs[n] * marg_llr[n];
        omeg0[i] = 1.0f - errors[b0 * NN + n];
        omeg1[i] = 1.0f - errors[b1 * NN + n];
    }

    // ---- register-held transposed weights (batch-shared) ----
    float mg0[VP], mg1[VP];
    #pragma unroll
    for (int jg = 0; jg < VG; ++jg) {
        float4 a = ((const float4*)marg_vT)[jg * NN + t];
        mg0[jg*4+0] = a.x; mg0[jg*4+1] = a.y; mg0[jg*4+2] = a.z; mg0[jg*4+3] = a.w;
        float4 c4 = ((const float4*)marg_vT)[jg * NN + t + NT];
        mg1[jg*4+0] = c4.x; mg1[jg*4+1] = c4.y; mg1[jg*4+2] = c4.z; mg1[jg*4+3] = c4.w;
    }
    float wcA0[VP], wcA1[VP], wcB0[VP], wcB1[VP];
    #pragma unroll
    for (int jg = 0; jg < VG; ++jg) {          // layer 0 -> A set
        float4 a = ((const float4*)wde_vT)[jg * NN + t];
        wcA0[jg*4+0] = a.x; wcA0[jg*4+1] = a.y; wcA0[jg*4+2] = a.z; wcA0[jg*4+3] = a.w;
        float4 c4 = ((const float4*)wde_vT)[jg * NN + t + NT];
        wcA1[jg*4+0] = c4.x; wcA1[jg*4+1] = c4.y; wcA1[jg*4+2] = c4.z; wcA1[jg*4+3] = c4.w;
    }
    float bcA[HE], bcB[HE];
    float tm0[HE], tm1[HE];
    {
        const float4 bp4 = ((const float4*)base_e_g)[t];   // layer 0
        bcA[0] = bp4.x; bcA[1] = bp4.y; bcA[2] = bp4.z; bcA[3] = bp4.w;
        #pragma unroll
        for (int k = 0; k < HE; ++k) { tm0[k] = bcA[k]; tm1[k] = bcA[k]; }
    }

    // ---- zero the exchange arrays (padding slots stay 0 forever) ----
    #pragma unroll
    for (int j = 0; j < 6; ++j) {
        ((float4*)s_cN0)[j * NT + t] = make_float4(0.f, 0.f, 0.f, 0.f);
        ((float4*)s_cN1)[j * NT + t] = make_float4(0.f, 0.f, 0.f, 0.f);
    }

    float loss = 0.0f;
    __syncthreads();

    // ---- layer loop, unrolled x2 with A/B register-set swap ----
    for (int l = 0; l < LL; l += 2) {
        LAYER_BODY(l,     wcA0, wcA1, wcB0, wcB1, bcB);
        LAYER_BODY(l + 1, wcB0, wcB1, wcA0, wcA1, bcA);
    }

    // tail: loss for the last layer, both batches (degree-gated, bit-exact)
    {
        const float rr = rhos[LL - 1];
        float bel00 = bias[0], bel01 = bias[1], bel10 = bias[0], bel11 = bias[1];
        {
            float4 a = ((const float4*)s_cN0)[t];
            float4 c4 = ((const float4*)s_cN0)[t + NT];
            bel00 += a.x*mg0[0] + a.y*mg0[1] + a.z*mg0[2] + a.w*mg0[3];
            bel01 += c4.x*mg1[0] + c4.y*mg1[1] + c4.z*mg1[2] + c4.w*mg1[3];
            float4 a1 = ((const float4*)s_cN1)[t];
            float4 c41 = ((const float4*)s_cN1)[t + NT];
            bel10 += a1.x*mg0[0] + a1.y*mg0[1] + a1.z*mg0[2] + a1.w*mg0[3];
            bel11 += c41.x*mg1[0] + c41.y*mg1[1] + c41.z*mg1[2] + c41.w*mg1[3];
        }
        if (deg0 > 4) {
            float4 a = ((const float4*)s_cN0)[NN + t];
            float4 c4 = ((const float4*)s_cN1)[NN + t];
            bel00 += a.x*mg0[4] + a.y*mg0[5] + a.z*mg0[6] + a.w*mg0[7];
            bel10 += c4.x*mg0[4] + c4.y*mg0[5] + c4.z*mg0[6] + c4.w*mg0[7];
        }
        if (deg1 > 4) {
            float4 a = ((const float4*)s_cN0)[NN + t + NT];
            float4 c4 = ((const float4*)s_cN1)[NN + t + NT];
            bel01 += a.x*mg1[4] + a.y*mg1[5] + a.z*mg1[6] + a.w*mg1[7];
            bel11 += c4.x*mg1[4] + c4.y*mg1[5] + c4.z*mg1[6] + c4.w*mg1[7];
        }
        if (deg0 > 8) {
            float4 a = ((const float4*)s_cN0)[2 * NN + t];
            float4 c4 = ((const float4*)s_cN1)[2 * NN + t];
            bel00 += a.x*mg0[8] + a.y*mg0[9] + a.z*mg0[10] + a.w*mg0[11];
            bel10 += c4.x*mg0[8] + c4.y*mg0[9] + c4.z*mg0[10] + c4.w*mg0[11];
        }
        if (deg1 > 8) {
            float4 a = ((const float4*)s_cN0)[2 * NN + t + NT];
            float4 c4 = ((const float4*)s_cN1)[2 * NN + t + NT];
            bel01 += a.x*mg1[8] + a.y*mg1[9] + a.z*mg1[10] + a.w*mg1[11];
            bel11 += c4.x*mg1[8] + c4.y*mg1[9] + c4.z*mg1[10] + c4.w*mg1[11];
        }
        float sp00 = fmaxf(bel00, 0.0f) + __logf(1.0f + __expf(-fabsf(bel00)));
        float sp01 = fmaxf(bel01, 0.0f) + __logf(1.0f + __expf(-fabsf(bel01)));
        float sp10 = fmaxf(bel10, 0.0f) + __logf(1.0f + __expf(-fabsf(bel10)));
        float sp11 = fmaxf(bel11, 0.0f) + __logf(1.0f + __expf(-fabsf(bel11)));
        loss += rr * ((sp00 - omeg0[0] * bel00) + (sp01 - omeg0[1] * bel01)
                    + (sp10 - omeg1[0] * bel10) + (sp11 - omeg1[1] * bel11));
    }

    // ---- block-wide loss reduction (12 waves) ----
    #pragma unroll
    for (int off = 32; off > 0; off >>= 1)
        loss += __shfl_down(loss, off, 64);
    int wave = t >> 6, lane = t & 63;
    if (lane == 0) s_red[wave] = loss;
    __syncthreads();
    if (t == 0) {
        float tot = 0.0f;
        #pragma unroll
        for (int w = 0; w < 12; ++w) tot += s_red[w];
        atomicAdd(out, tot * (1.0f / (float)MB));
    }
}

// ---------------------------------------------------------------------------
extern "C" void kernel_launch(void* const* d_in, const int* in_sizes, int n_in,
                              void* d_out, int out_size, void* d_ws, size_t ws_size,
                              hipStream_t stream) {
    const float* synd     = (const float*)d_in[0];
    const float* errors   = (const float*)d_in[1];
    const float* H        = (const float*)d_in[2];
    const float* llrs     = (const float*)d_in[3];
    const float* w_de     = (const float*)d_in[4];
    const float* w_llr    = (const float*)d_in[5];
    const float* marg_de  = (const float*)d_in[6];
    const float* marg_llr = (const float*)d_in[7];
    const float* res_w    = (const float*)d_in[8];
    const float* rhos     = (const float*)d_in[9];
    float* out = (float*)d_out;

    float* wde_vT  = (float*)d_ws;
    float* marg_vT = wde_vT + (size_t)LL * VG * NN * 4;
    int*   gcnt    = (int*)(marg_vT + VG * NN * 4);
    float* base_e  = (float*)(gcnt + NN);
    int*   col_pack= (int*)(base_e + (size_t)LL * NE);

    hipMemsetAsync(gcnt, 0, NN * sizeof(int), stream);
    setup_kernel<<<MM, 256, 0, stream>>>(H, llrs, w_llr, w_de, marg_de,
                                         col_pack, base_e, wde_vT, marg_vT,
                                         gcnt, out);
    bp_kernel<<<MB / 2, NT, 0, stream>>>(synd, errors, llrs, marg_llr, res_w,
                                         rhos, col_pack, base_e, wde_vT,
                                         marg_vT, gcnt, out);
}

// Round 7
// 146.340 us; speedup vs baseline: 1.0599x; 1.0599x over previous
//
#include <hip/hip_runtime.h>
#include <math.h>

// Problem constants (match reference)
#define MB 8      // batch
#define MM 384    // checks
#define NN 1536   // variables
#define LL 20     // layers
#define RW 8      // row weight of H
#define HE 4      // edges per thread (half row)
#define NE (MM*RW)  // 3072 edges
#define NT 768    // bp block size (2 threads per check row)
#define VP 12     // max column degree supported (validated: never hit)
#define VG 3      // VP/4 float4 groups

#define LOG2E 1.44269504f
#define LN2   0.69314718f

// Soft barrier: LDS visibility only (s_waitcnt lgkmcnt(0) + s_barrier).
// Deliberately does NOT drain vmcnt — global prefetches stay in flight.
#define SOFT_BAR() asm volatile("s_waitcnt lgkmcnt(0)\n\ts_barrier" ::: "memory")

// Lane xor-1 exchange via DPP quad_perm(1,0,3,2): pure VALU.
static __device__ __forceinline__ float dpp_xor1(float x) {
    return __int_as_float(
        __builtin_amdgcn_mov_dpp(__float_as_int(x), 0xB1, 0xF, 0xF, true));
}

// ---------------------------------------------------------------------------
// Fused setup: one block (256 thr = 4 waves) per check row.
// R7 addition: CSC edge-list cse[c*VP + pos] = edge id (m*RW+k), used by
// bp owners to broadcast S into edge-indexed LDS slots.
// ---------------------------------------------------------------------------
__global__ __launch_bounds__(256) void setup_kernel(
    const float* __restrict__ H,
    const float* __restrict__ llrs,
    const float* __restrict__ w_llr,
    const float* __restrict__ w_de,
    const float* __restrict__ marg_de,
    int*   __restrict__ col_pack,
    float* __restrict__ base_e,
    float* __restrict__ wde_vT,
    float* __restrict__ marg_vT,
    int*   __restrict__ gcnt,
    int*   __restrict__ cse,
    float* __restrict__ out) {
    const int m = blockIdx.x;
    const int t = threadIdx.x;
    const int w = t >> 6, lane = t & 63;
    __shared__ int s_qcol[4][RW];
    __shared__ int s_qcnt[4];
    __shared__ int s_col[RW];
    __shared__ int s_pos[RW];

    const float* row = H + (size_t)m * NN;
    int count = 0;
    for (int c0 = w * 384; c0 < (w + 1) * 384; c0 += 64) {
        float v = row[c0 + lane];
        unsigned long long mask = __ballot(v != 0.0f);
        if (v != 0.0f) {
            int pos = count + (int)__popcll(mask & ((1ull << lane) - 1ull));
            if (pos < RW) s_qcol[w][pos] = c0 + lane;
        }
        count += (int)__popcll(mask);
    }
    if (lane == 0) s_qcnt[w] = (count < RW) ? count : RW;
    __syncthreads();
    if (t == 0) {
        int off = 0;
        for (int q = 0; q < 4; ++q)
            for (int i = 0; i < s_qcnt[q]; ++i) {
                if (off < RW) s_col[off] = s_qcol[q][i];
                ++off;
            }
    }
    __syncthreads();

    if (t < RW) {
        int c = s_col[t];
        int pos = atomicAdd(&gcnt[c], 1);
        if (pos >= VP) pos = VP - 1;   // clamp (validated: never hit)
        // CSC edge list (dense by arrival order pos)
        cse[c * VP + pos] = m * RW + t;
        // bank-conflict swizzle of the intra-group slot position (s_cN only)
        int ps = (pos & ~3) | ((pos & 3) ^ ((c >> 3) & 3));
        s_pos[t] = ps;
        col_pack[m * RW + t] = c | (ps << 16);
        // messages live in log2 domain -> marg weight carries ln2
        marg_vT[((ps >> 2) * NN + c) * 4 + (ps & 3)] = marg_de[m * NN + c] * LN2;
    }
    if (m == 0 && t == 0) out[0] = 0.0f;
    __syncthreads();

    for (int idx = t; idx < LL * RW; idx += 256) {
        int l = idx >> 3;
        int k = idx & 7;
        int c = s_col[k];
        int ps = s_pos[k];
        wde_vT[((l * VG + (ps >> 2)) * NN + c) * 4 + (ps & 3)] =
            w_de[(size_t)l * MM * NN + (size_t)m * NN + c];
        // base in log2 domain
        base_e[l * NE + m * RW + k] = llrs[c] * w_llr[l * NN + c] * LOG2E;
    }
}

// ===========================================================================
// One full layer body (x2-unrolled register-set swap).
// Phase A: global prefetch; owner gather -> S; owner BROADCASTS S into
//          edge-indexed s_Se slots (scattered writes, pre-barrier slack);
//          group-0 msg float4s held in regs across the barrier.
// Phase B: ONE conflict-free ds_read_b128 of s_Se (this thread's 4 edges);
//          loss softplus fills its latency; check chain via the exact
//          identity 2*atanh(P/d) = log2(d+P) - log2(d-P), P = row product.
// ===========================================================================
#define LAYER_BODY(lv, WC0, WC1, WN0, WN1, BN)                                \
{                                                                             \
    /* phase A: prefetch next layer's wde_vT and base_e (stays in flight) */  \
    {                                                                         \
        int lb = ((lv) + 1 < LL) ? ((lv) + 1) : (LL - 1);                     \
        _Pragma("unroll")                                                     \
        for (int jg = 0; jg < VG; ++jg) {                                     \
            float4 a = ((const float4*)wde_vT)[(lb * VG + jg) * NN + t];      \
            WN0[jg*4+0]=a.x; WN0[jg*4+1]=a.y; WN0[jg*4+2]=a.z; WN0[jg*4+3]=a.w; \
            float4 c4 = ((const float4*)wde_vT)[(lb * VG + jg) * NN + t + NT];\
            WN1[jg*4+0]=c4.x; WN1[jg*4+1]=c4.y; WN1[jg*4+2]=c4.z; WN1[jg*4+3]=c4.w; \
        }                                                                     \
        const float4 bp4 = ((const float4*)(base_e_g + lb * NE))[t];          \
        BN[0]=bp4.x; BN[1]=bp4.y; BN[2]=bp4.z; BN[3]=bp4.w;                   \
    }                                                                         \
    /* owner gather: S now; group-0 belief deferred to phase B */             \
    float4 g0a = ((const float4*)s_cN)[t];                                    \
    float4 g0b = ((const float4*)s_cN)[t + NT];                               \
    float belx0 = bias[0], belx1 = bias[1];                                   \
    {                                                                         \
        float S0 = g0a.x*WC0[0] + g0a.y*WC0[1] + g0a.z*WC0[2] + g0a.w*WC0[3]; \
        float S1 = g0b.x*WC1[0] + g0b.y*WC1[1] + g0b.z*WC1[2] + g0b.w*WC1[3]; \
        if (deg0 > 4) {                                                       \
            float4 a = ((const float4*)s_cN)[NN + t];                         \
            S0    += a.x*WC0[4] + a.y*WC0[5] + a.z*WC0[6] + a.w*WC0[7];       \
            belx0 += a.x*mg0[4] + a.y*mg0[5] + a.z*mg0[6] + a.w*mg0[7];       \
        }                                                                     \
        if (deg1 > 4) {                                                       \
            float4 c4 = ((const float4*)s_cN)[NN + t + NT];                   \
            S1    += c4.x*WC1[4] + c4.y*WC1[5] + c4.z*WC1[6] + c4.w*WC1[7];   \
            belx1 += c4.x*mg1[4] + c4.y*mg1[5] + c4.z*mg1[6] + c4.w*mg1[7];   \
        }                                                                     \
        if (deg0 > 8) {                                                       \
            float4 a = ((const float4*)s_cN)[2 * NN + t];                     \
            S0    += a.x*WC0[8] + a.y*WC0[9] + a.z*WC0[10] + a.w*WC0[11];     \
            belx0 += a.x*mg0[8] + a.y*mg0[9] + a.z*mg0[10] + a.w*mg0[11];     \
        }                                                                     \
        if (deg1 > 8) {                                                       \
            float4 c4 = ((const float4*)s_cN)[2 * NN + t + NT];               \
            S1    += c4.x*WC1[8] + c4.y*WC1[9] + c4.z*WC1[10] + c4.w*WC1[11]; \
            belx1 += c4.x*mg1[8] + c4.y*mg1[9] + c4.z*mg1[10] + c4.w*mg1[11]; \
        }                                                                     \
        /* broadcast S to edge-indexed slots (invalid -> per-lane dump) */    \
        s_Se[ce0[0]] = S0; s_Se[ce0[1]] = S0;                                 \
        s_Se[ce0[2]] = S0; s_Se[ce0[3]] = S0;                                 \
        s_Se[ce1[0]] = S1; s_Se[ce1[1]] = S1;                                 \
        s_Se[ce1[2]] = S1; s_Se[ce1[3]] = S1;                                 \
        if (deg0 > 4) { s_Se[ce0[4]] = S0; s_Se[ce0[5]] = S0;                 \
                        s_Se[ce0[6]] = S0; s_Se[ce0[7]] = S0; }               \
        if (deg1 > 4) { s_Se[ce1[4]] = S1; s_Se[ce1[5]] = S1;                 \
                        s_Se[ce1[6]] = S1; s_Se[ce1[7]] = S1; }               \
        if (deg0 > 8) { s_Se[ce0[8]] = S0; s_Se[ce0[9]] = S0;                 \
                        s_Se[ce0[10]] = S0; s_Se[ce0[11]] = S0; }             \
        if (deg1 > 8) { s_Se[ce1[8]] = S1; s_Se[ce1[9]] = S1;                 \
                        s_Se[ce1[10]] = S1; s_Se[ce1[11]] = S1; }             \
    }                                                                         \
    SOFT_BAR();   /* barrier A: s_Se visible; old s_cN consumed (in regs) */  \
    {                                                                         \
        /* ONE conflict-free vector read: this thread's 4 edge sums */        \
        const float4 ssv = ((const float4*)s_Se)[t];                          \
        /* filler: group-0 belief + loss for layer lv-1 */                    \
        if ((lv) > 0) {                                                       \
            const float rr = rhos[(lv) - 1];                                  \
            float bel0 = belx0 + g0a.x*mg0[0] + g0a.y*mg0[1]                  \
                               + g0a.z*mg0[2] + g0a.w*mg0[3];                 \
            float bel1 = belx1 + g0b.x*mg1[0] + g0b.y*mg1[1]                  \
                               + g0b.z*mg1[2] + g0b.w*mg1[3];                 \
            float sp0 = fmaxf(bel0, 0.0f) + __logf(1.0f + __expf(-fabsf(bel0))); \
            float sp1 = fmaxf(bel1, 0.0f) + __logf(1.0f + __expf(-fabsf(bel1))); \
            loss += rr * ((sp0 - omeg[0] * bel0) + (sp1 - omeg[1] * bel1));   \
        }                                                                     \
        const float rw_ = res_w[(lv)];                                        \
        float ss[HE] = {ssv.x, ssv.y, ssv.z, ssv.w};                          \
        float d[HE];                                                          \
        _Pragma("unroll")                                                     \
        for (int k = 0; k < HE; ++k) {                                        \
            float te = tm[k] + ss[k];                /* log2 domain */        \
            float e  = __builtin_amdgcn_exp2f(te);                            \
            float dd = 1.0f - 2.0f * __builtin_amdgcn_rcpf(e + 1.0f);         \
            dd = fminf(fmaxf(dd, -1.0f), 1.0f);                               \
            if (dd == 0.0f) dd = 1.0f;                                        \
            d[k] = dd;                                                        \
        }                                                                     \
        float p4 = (d[0] * d[1]) * (d[2] * d[3]);                             \
        float P  = p4 * dpp_xor1(p4);    /* full 8-edge row product */        \
        _Pragma("unroll")                                                     \
        for (int k = 0; k < HE; ++k) {                                        \
            /* 2*atanh(P/d) = log((d+P)/(d-P)); exact, no exclusion prods */  \
            float la  = __builtin_amdgcn_logf(fabsf(d[k] + P));               \
            float lb2 = __builtin_amdgcn_logf(fabsf(d[k] - P));               \
            float nm = sgn * (la - lb2) + rw_ * msg[k];   /* log2 domain */   \
            msg[k] = nm;                                                      \
            s_cN[esl[k]] = nm;                                                \
        }                                                                     \
        /* prefold next layer's te base (off critical path) */                \
        _Pragma("unroll")                                                     \
        for (int k = 0; k < HE; ++k) tm[k] = BN[k] - msg[k];                  \
    }                                                                         \
    SOFT_BAR();   /* barrier B: s_cN visible for next gather */               \
}

// ---------------------------------------------------------------------------
// Main BP kernel: 8 blocks, 768 threads = 2 per check row (4 edges each).
// Zero atomics; swizzled CSC-padded LDS exchange; owner->edge S broadcast;
// 2 SOFT barriers/layer; x2 unroll; degree-gated gather; DPP row product;
// log2-domain messages; (d+P)/(d-P) self-exclusion.
// ---------------------------------------------------------------------------
__global__ __launch_bounds__(NT) void bp_kernel(
    const float* __restrict__ synd,       // (B,M,1)
    const float* __restrict__ errors,     // (B,N)
    const float* __restrict__ llrs,       // (N)
    const float* __restrict__ marg_llr,   // (N)
    const float* __restrict__ res_w,      // (L)
    const float* __restrict__ rhos,       // (L)
    const int*   __restrict__ col_pack,   // (E)  c | pos<<16 (swizzled pos)
    const float* __restrict__ base_e_g,   // (L,E)  log2-scaled
    const float* __restrict__ wde_vT,     // (L,VG,N,4)  swizzled elements
    const float* __restrict__ marg_vT,    // (VG,N,4)  ln2-scaled, swizzled
    const int*   __restrict__ gdeg,       // (N)  column degrees (= gcnt)
    const int*   __restrict__ cse,        // (N,VP) CSC edge ids
    float* __restrict__ out) {

    __shared__ float s_cN[NN * VP];       // 72 KB  edge messages, CSC-padded
    __shared__ __align__(16) float s_Se[NE + 64];  // 12.25 KB edge-indexed S
    __shared__ float s_red[12];

    const int b = blockIdx.x;
    const int t = threadIdx.x;
    const int m = t >> 1;        // check row

    // ---- per-edge register state ----
    int col[HE], esl[HE];
    {
        const int4 cp = ((const int4*)col_pack)[t];
        int v[HE] = {cp.x, cp.y, cp.z, cp.w};
        #pragma unroll
        for (int k = 0; k < HE; ++k) {
            int c = v[k] & 0xFFFF, pos = v[k] >> 16;
            col[k] = c;
            esl[k] = ((pos >> 2) * NN + c) * 4 + (pos & 3);
        }
    }
    float msg[HE] = {0.0f, 0.0f, 0.0f, 0.0f};
    const float sgn = 1.0f - 2.0f * synd[b * MM + m];

    // ---- owned-variable state ----
    const int deg0 = gdeg[t];
    const int deg1 = gdeg[t + NT];
    float bias[2], omeg[2];
    #pragma unroll
    for (int i = 0; i < 2; ++i) {
        int n = t + i * NT;
        bias[i] = llrs[n] * marg_llr[n];
        omeg[i] = 1.0f - errors[b * NN + n];
    }

    // ---- CSC edge lists for owned variables (invalid -> per-lane dump) ----
    int ce0[VP], ce1[VP];
    {
        const int4* cb0 = (const int4*)(cse + (size_t)t * VP);
        const int4* cb1 = (const int4*)(cse + (size_t)(t + NT) * VP);
        int4 g;
        g = cb0[0]; ce0[0]=g.x; ce0[1]=g.y; ce0[2]=g.z; ce0[3]=g.w;
        g = cb0[1]; ce0[4]=g.x; ce0[5]=g.y; ce0[6]=g.z; ce0[7]=g.w;
        g = cb0[2]; ce0[8]=g.x; ce0[9]=g.y; ce0[10]=g.z; ce0[11]=g.w;
        g = cb1[0]; ce1[0]=g.x; ce1[1]=g.y; ce1[2]=g.z; ce1[3]=g.w;
        g = cb1[1]; ce1[4]=g.x; ce1[5]=g.y; ce1[6]=g.z; ce1[7]=g.w;
        g = cb1[2]; ce1[8]=g.x; ce1[9]=g.y; ce1[10]=g.z; ce1[11]=g.w;
        const int dump = NE + (t & 63);
        #pragma unroll
        for (int j = 0; j < VP; ++j) {
            ce0[j] = (j < deg0) ? ce0[j] : dump;
            ce1[j] = (j < deg1) ? ce1[j] : dump;
        }
    }

    // ---- register-held transposed weights for owned variables t, t+NT ----
    float mg0[VP], mg1[VP];
    #pragma unroll
    for (int jg = 0; jg < VG; ++jg) {
        float4 a = ((const float4*)marg_vT)[jg * NN + t];
        mg0[jg*4+0] = a.x; mg0[jg*4+1] = a.y; mg0[jg*4+2] = a.z; mg0[jg*4+3] = a.w;
        float4 c4 = ((const float4*)marg_vT)[jg * NN + t + NT];
        mg1[jg*4+0] = c4.x; mg1[jg*4+1] = c4.y; mg1[jg*4+2] = c4.z; mg1[jg*4+3] = c4.w;
    }
    float wcA0[VP], wcA1[VP], wcB0[VP], wcB1[VP];
    #pragma unroll
    for (int jg = 0; jg < VG; ++jg) {          // layer 0 -> A set
        float4 a = ((const float4*)wde_vT)[jg * NN + t];
        wcA0[jg*4+0] = a.x; wcA0[jg*4+1] = a.y; wcA0[jg*4+2] = a.z; wcA0[jg*4+3] = a.w;
        float4 c4 = ((const float4*)wde_vT)[jg * NN + t + NT];
        wcA1[jg*4+0] = c4.x; wcA1[jg*4+1] = c4.y; wcA1[jg*4+2] = c4.z; wcA1[jg*4+3] = c4.w;
    }
    float bcA[HE], bcB[HE];
    float tm[HE];
    {
        const float4 bp4 = ((const float4*)base_e_g)[t];   // layer 0
        bcA[0] = bp4.x; bcA[1] = bp4.y; bcA[2] = bp4.z; bcA[3] = bp4.w;
        #pragma unroll
        for (int k = 0; k < HE; ++k) tm[k] = bcA[k];       // msg == 0
    }

    // ---- zero the exchange array (padding slots stay 0 forever) ----
    #pragma unroll
    for (int j = 0; j < 6; ++j)
        ((float4*)s_cN)[j * NT + t] = make_float4(0.f, 0.f, 0.f, 0.f);

    float loss = 0.0f;
    __syncthreads();

    // ---- layer loop, unrolled x2 with A/B register-set swap ----
    for (int l = 0; l < LL; l += 2) {
        LAYER_BODY(l,     wcA0, wcA1, wcB0, wcB1, bcB);
        LAYER_BODY(l + 1, wcB0, wcB1, wcA0, wcA1, bcA);
    }

    // tail: loss for the last layer (degree-gated, bit-exact)
    {
        const float rr = rhos[LL - 1];
        float bel0 = bias[0], bel1 = bias[1];
        {
            float4 a = ((const float4*)s_cN)[t];
            bel0 += a.x*mg0[0] + a.y*mg0[1] + a.z*mg0[2] + a.w*mg0[3];
            float4 c4 = ((const float4*)s_cN)[t + NT];
            bel1 += c4.x*mg1[0] + c4.y*mg1[1] + c4.z*mg1[2] + c4.w*mg1[3];
        }
        if (deg0 > 4) {
            float4 a = ((const float4*)s_cN)[NN + t];
            bel0 += a.x*mg0[4] + a.y*mg0[5] + a.z*mg0[6] + a.w*mg0[7];
        }
        if (deg1 > 4) {
            float4 c4 = ((const float4*)s_cN)[NN + t + NT];
            bel1 += c4.x*mg1[4] + c4.y*mg1[5] + c4.z*mg1[6] + c4.w*mg1[7];
        }
        if (deg0 > 8) {
            float4 a = ((const float4*)s_cN)[2 * NN + t];
            bel0 += a.x*mg0[8] + a.y*mg0[9] + a.z*mg0[10] + a.w*mg0[11];
        }
        if (deg1 > 8) {
            float4 c4 = ((const float4*)s_cN)[2 * NN + t + NT];
            bel1 += c4.x*mg1[8] + c4.y*mg1[9] + c4.z*mg1[10] + c4.w*mg1[11];
        }
        float sp0 = fmaxf(bel0, 0.0f) + __logf(1.0f + __expf(-fabsf(bel0)));
        float sp1 = fmaxf(bel1, 0.0f) + __logf(1.0f + __expf(-fabsf(bel1)));
        loss += rr * ((sp0 - omeg[0] * bel0) + (sp1 - omeg[1] * bel1));
    }

    // ---- block-wide loss reduction (12 waves) ----
    #pragma unroll
    for (int off = 32; off > 0; off >>= 1)
        loss += __shfl_down(loss, off, 64);
    int wave = t >> 6, lane = t & 63;
    if (lane == 0) s_red[wave] = loss;
    __syncthreads();
    if (t == 0) {
        float tot = 0.0f;
        #pragma unroll
        for (int w = 0; w < 12; ++w) tot += s_red[w];
        atomicAdd(out, tot * (1.0f / (float)MB));
    }
}

// ---------------------------------------------------------------------------
extern "C" void kernel_launch(void* const* d_in, const int* in_sizes, int n_in,
                              void* d_out, int out_size, void* d_ws, size_t ws_size,
                              hipStream_t stream) {
    const float* synd     = (const float*)d_in[0];
    const float* errors   = (const float*)d_in[1];
    const float* H        = (const float*)d_in[2];
    const float* llrs     = (const float*)d_in[3];
    const float* w_de     = (const float*)d_in[4];
    const float* w_llr    = (const float*)d_in[5];
    const float* marg_de  = (const float*)d_in[6];
    const float* marg_llr = (const float*)d_in[7];
    const float* res_w    = (const float*)d_in[8];
    const float* rhos     = (const float*)d_in[9];
    float* out = (float*)d_out;

    float* wde_vT  = (float*)d_ws;
    float* marg_vT = wde_vT + (size_t)LL * VG * NN * 4;
    int*   gcnt    = (int*)(marg_vT + VG * NN * 4);
    float* base_e  = (float*)(gcnt + NN);
    int*   col_pack= (int*)(base_e + (size_t)LL * NE);
    int*   cse     = (int*)(col_pack + NE);

    hipMemsetAsync(gcnt, 0, NN * sizeof(int), stream);
    setup_kernel<<<MM, 256, 0, stream>>>(H, llrs, w_llr, w_de, marg_de,
                                         col_pack, base_e, wde_vT, marg_vT,
                                         gcnt, cse, out);
    bp_kernel<<<MB, NT, 0, stream>>>(synd, errors, llrs, marg_llr, res_w, rhos,
                                     col_pack, base_e, wde_vT, marg_vT, gcnt,
                                     cse, out);
}

// Round 8
// 131.804 us; speedup vs baseline: 1.1768x; 1.1103x over previous
//
#include <hip/hip_runtime.h>
#include <math.h>

// Problem constants (match reference)
#define MB 8      // batch
#define MM 384    // checks
#define NN 1536   // variables
#define LL 20     // layers
#define RW 8      // row weight of H
#define HE 4      // edges per thread (half row)
#define NE (MM*RW)  // 3072 edges
#define NT 768    // bp block size (2 threads per check row)
#define VP 12     // max column degree supported (validated: never hit)
#define VG 3      // VP/4 float4 groups

#define LOG2E 1.44269504f
#define LN2   0.69314718f

// Soft barrier: LDS visibility only (s_waitcnt lgkmcnt(0) + s_barrier).
// Deliberately does NOT drain vmcnt — global prefetches stay in flight.
#define SOFT_BAR() asm volatile("s_waitcnt lgkmcnt(0)\n\ts_barrier" ::: "memory")

// Lane xor-1 exchange via DPP quad_perm(1,0,3,2): pure VALU.
static __device__ __forceinline__ float dpp_xor1(float x) {
    return __int_as_float(
        __builtin_amdgcn_mov_dpp(__float_as_int(x), 0xB1, 0xF, 0xF, true));
}

// ---------------------------------------------------------------------------
// Fused setup: one block (256 thr = 4 waves) per check row.
// R8: weights emitted EDGE-ordered only (wde_e (L,E), marg_e (E)) — the
// padded column-transposed wde_vT (6x fetch waste on the BW-bound stream)
// is gone. bp multiplies check-side.
// ---------------------------------------------------------------------------
__global__ __launch_bounds__(256) void setup_kernel(
    const float* __restrict__ H,
    const float* __restrict__ llrs,
    const float* __restrict__ w_llr,
    const float* __restrict__ w_de,
    const float* __restrict__ marg_de,
    int*   __restrict__ col_pack,
    float* __restrict__ base_e,
    float* __restrict__ wde_e,
    float* __restrict__ marg_e,
    int*   __restrict__ gcnt,
    float* __restrict__ out) {
    const int m = blockIdx.x;
    const int t = threadIdx.x;
    const int w = t >> 6, lane = t & 63;
    __shared__ int s_qcol[4][RW];
    __shared__ int s_qcnt[4];
    __shared__ int s_col[RW];

    const float* row = H + (size_t)m * NN;
    int count = 0;
    for (int c0 = w * 384; c0 < (w + 1) * 384; c0 += 64) {
        float v = row[c0 + lane];
        unsigned long long mask = __ballot(v != 0.0f);
        if (v != 0.0f) {
            int pos = count + (int)__popcll(mask & ((1ull << lane) - 1ull));
            if (pos < RW) s_qcol[w][pos] = c0 + lane;
        }
        count += (int)__popcll(mask);
    }
    if (lane == 0) s_qcnt[w] = (count < RW) ? count : RW;
    __syncthreads();
    if (t == 0) {
        int off = 0;
        for (int q = 0; q < 4; ++q)
            for (int i = 0; i < s_qcnt[q]; ++i) {
                if (off < RW) s_col[off] = s_qcol[q][i];
                ++off;
            }
    }
    __syncthreads();

    if (t < RW) {
        int c = s_col[t];
        int pos = atomicAdd(&gcnt[c], 1);
        if (pos >= VP) pos = VP - 1;   // clamp (validated: never hit)
        // bank-conflict swizzle of the intra-group slot position
        int ps = (pos & ~3) | ((pos & 3) ^ ((c >> 3) & 3));
        col_pack[m * RW + t] = c | (ps << 16);
        // messages live in log2 domain -> marg weight carries ln2
        marg_e[m * RW + t] = marg_de[m * NN + c] * LN2;
    }
    if (m == 0 && t == 0) out[0] = 0.0f;
    __syncthreads();

    for (int idx = t; idx < LL * RW; idx += 256) {
        int l = idx >> 3;
        int k = idx & 7;
        int c = s_col[k];
        wde_e[l * NE + m * RW + k] = w_de[(size_t)l * MM * NN + (size_t)m * NN + c];
        // base in log2 domain
        base_e[l * NE + m * RW + k] = llrs[c] * w_llr[l * NN + c] * LOG2E;
    }
}

// ===========================================================================
// One full layer body (x2-unrolled prefetch-buffer swap).
// Check thread writes TWO pre-weighted copies of its message:
//   s_cW[esl] = nm * wde_e[l+1][edge]   (next gather's S term)
//   s_cM[esl] = nm * marg_e[edge]       (belief term)
// Owner gather is pure slot-sum (adds only, no weight regs, no fetch).
// Per-layer global traffic: 2 coalesced float4/thread (wde_e, base_e).
// ===========================================================================
#define LAYER_BODY(lv, WNC, WNN, BN)                                          \
{                                                                             \
    /* prefetch: wde_e[lv+2] and base_e[lv+1] (stay in flight) */             \
    {                                                                         \
        int la2 = ((lv) + 2 < LL) ? ((lv) + 2) : (LL - 1);                    \
        const float4 w4 = ((const float4*)(wde_e_g + la2 * NE))[t];           \
        WNN[0]=w4.x; WNN[1]=w4.y; WNN[2]=w4.z; WNN[3]=w4.w;                   \
        int lb = ((lv) + 1 < LL) ? ((lv) + 1) : (LL - 1);                     \
        const float4 bp4 = ((const float4*)(base_e_g + lb * NE))[t];          \
        BN[0]=bp4.x; BN[1]=bp4.y; BN[2]=bp4.z; BN[3]=bp4.w;                   \
    }                                                                         \
    /* phase A: owner slot-sums; group-0 belief quad held for phase B */      \
    float4 m0a = ((const float4*)s_cM)[t];                                    \
    float4 m0b = ((const float4*)s_cM)[t + NT];                               \
    float belx0 = bias[0], belx1 = bias[1];                                   \
    {                                                                         \
        float4 w0a = ((const float4*)s_cW)[t];                                \
        float4 w0b = ((const float4*)s_cW)[t + NT];                           \
        float S0 = (w0a.x + w0a.y) + (w0a.z + w0a.w);                         \
        float S1 = (w0b.x + w0b.y) + (w0b.z + w0b.w);                         \
        if (deg0 > 4) {                                                       \
            float4 a = ((const float4*)s_cW)[NN + t];                         \
            float4 q = ((const float4*)s_cM)[NN + t];                         \
            S0    += (a.x + a.y) + (a.z + a.w);                               \
            belx0 += (q.x + q.y) + (q.z + q.w);                               \
        }                                                                     \
        if (deg1 > 4) {                                                       \
            float4 a = ((const float4*)s_cW)[NN + t + NT];                    \
            float4 q = ((const float4*)s_cM)[NN + t + NT];                    \
            S1    += (a.x + a.y) + (a.z + a.w);                               \
            belx1 += (q.x + q.y) + (q.z + q.w);                               \
        }                                                                     \
        if (deg0 > 8) {                                                       \
            float4 a = ((const float4*)s_cW)[2 * NN + t];                     \
            float4 q = ((const float4*)s_cM)[2 * NN + t];                     \
            S0    += (a.x + a.y) + (a.z + a.w);                               \
            belx0 += (q.x + q.y) + (q.z + q.w);                               \
        }                                                                     \
        if (deg1 > 8) {                                                       \
            float4 a = ((const float4*)s_cW)[2 * NN + t + NT];                \
            float4 q = ((const float4*)s_cM)[2 * NN + t + NT];                \
            S1    += (a.x + a.y) + (a.z + a.w);                               \
            belx1 += (q.x + q.y) + (q.z + q.w);                               \
        }                                                                     \
        s_S[t]      = S0;                                                     \
        s_S[t + NT] = S1;                                                     \
    }                                                                         \
    SOFT_BAR();   /* barrier A: s_S visible; old s_cW/s_cM consumed */        \
    {                                                                         \
        /* issue the scattered s_S reads first */                             \
        float ss[HE];                                                         \
        _Pragma("unroll")                                                     \
        for (int k = 0; k < HE; ++k) ss[k] = s_S[col[k]];                     \
        /* filler: group-0 belief + loss for layer lv-1 */                    \
        if ((lv) > 0) {                                                       \
            const float rr = rhos[(lv) - 1];                                  \
            float bel0 = belx0 + (m0a.x + m0a.y) + (m0a.z + m0a.w);           \
            float bel1 = belx1 + (m0b.x + m0b.y) + (m0b.z + m0b.w);           \
            float sp0 = fmaxf(bel0, 0.0f) + __logf(1.0f + __expf(-fabsf(bel0))); \
            float sp1 = fmaxf(bel1, 0.0f) + __logf(1.0f + __expf(-fabsf(bel1))); \
            loss += rr * ((sp0 - omeg[0] * bel0) + (sp1 - omeg[1] * bel1));   \
        }                                                                     \
        const float rw_ = res_w[(lv)];                                        \
        float d[HE];                                                          \
        _Pragma("unroll")                                                     \
        for (int k = 0; k < HE; ++k) {                                        \
            float te = tm[k] + ss[k];                /* log2 domain */        \
            float e  = __builtin_amdgcn_exp2f(te);                            \
            float dd = 1.0f - 2.0f * __builtin_amdgcn_rcpf(e + 1.0f);         \
            dd = fminf(fmaxf(dd, -1.0f), 1.0f);                               \
            if (dd == 0.0f) dd = 1.0f;                                        \
            d[k] = dd;                                                        \
        }                                                                     \
        float p4 = (d[0] * d[1]) * (d[2] * d[3]);                             \
        float P  = p4 * dpp_xor1(p4);    /* full 8-edge row product */        \
        _Pragma("unroll")                                                     \
        for (int k = 0; k < HE; ++k) {                                        \
            /* 2*atanh(P/d) = log((d+P)/(d-P)); exact, no exclusion prods */  \
            float la  = __builtin_amdgcn_logf(fabsf(d[k] + P));               \
            float lb2 = __builtin_amdgcn_logf(fabsf(d[k] - P));               \
            float nm = sgn * (la - lb2) + rw_ * msg[k];   /* log2 domain */   \
            msg[k] = nm;                                                      \
            s_cW[esl[k]] = nm * WNC[k];   /* pre-weighted for next S */       \
            s_cM[esl[k]] = nm * me[k];    /* pre-weighted for beliefs */      \
        }                                                                     \
        /* prefold next layer's te base (off critical path) */                \
        _Pragma("unroll")                                                     \
        for (int k = 0; k < HE; ++k) tm[k] = BN[k] - msg[k];                  \
    }                                                                         \
    SOFT_BAR();   /* barrier B: s_cW/s_cM visible for next gather */          \
}

// ---------------------------------------------------------------------------
// Main BP kernel: 8 blocks, 768 threads = 2 per check row (4 edges each).
// Zero atomics; dual pre-weighted swizzled CSC exchange; 2 SOFT barriers
// per layer; x2 unroll; degree-gated slot-sum gather; DPP row product;
// log2-domain messages; (d+P)/(d-P) self-exclusion.
// ---------------------------------------------------------------------------
__global__ __launch_bounds__(NT) void bp_kernel(
    const float* __restrict__ synd,       // (B,M,1)
    const float* __restrict__ errors,     // (B,N)
    const float* __restrict__ llrs,       // (N)
    const float* __restrict__ marg_llr,   // (N)
    const float* __restrict__ res_w,      // (L)
    const float* __restrict__ rhos,       // (L)
    const int*   __restrict__ col_pack,   // (E)  c | pos<<16 (swizzled pos)
    const float* __restrict__ base_e_g,   // (L,E)  log2-scaled
    const float* __restrict__ wde_e_g,    // (L,E)  edge-ordered
    const float* __restrict__ marg_e_g,   // (E)    edge-ordered, ln2-scaled
    const int*   __restrict__ gdeg,       // (N)  column degrees (= gcnt)
    float* __restrict__ out) {

    __shared__ float s_cW[NN * VP];       // 72 KB  wde-weighted messages
    __shared__ float s_cM[NN * VP];       // 72 KB  marg-weighted messages
    __shared__ float s_S[NN];             // 6 KB   variable sums
    __shared__ float s_red[12];

    const int b = blockIdx.x;
    const int t = threadIdx.x;
    const int m = t >> 1;        // check row

    // ---- per-edge register state ----
    int col[HE], esl[HE];
    {
        const int4 cp = ((const int4*)col_pack)[t];
        int v[HE] = {cp.x, cp.y, cp.z, cp.w};
        #pragma unroll
        for (int k = 0; k < HE; ++k) {
            int c = v[k] & 0xFFFF, pos = v[k] >> 16;
            col[k] = c;
            esl[k] = ((pos >> 2) * NN + c) * 4 + (pos & 3);
        }
    }
    float msg[HE] = {0.0f, 0.0f, 0.0f, 0.0f};
    const float sgn = 1.0f - 2.0f * synd[b * MM + m];

    // ---- owned-variable state ----
    const int deg0 = gdeg[t];
    const int deg1 = gdeg[t + NT];
    float bias[2], omeg[2];
    #pragma unroll
    for (int i = 0; i < 2; ++i) {
        int n = t + i * NT;
        bias[i] = llrs[n] * marg_llr[n];
        omeg[i] = 1.0f - errors[b * NN + n];
    }

    // ---- static edge weights (marg) + first wde prefetch buffer ----
    float me[HE];
    {
        const float4 m4 = ((const float4*)marg_e_g)[t];
        me[0] = m4.x; me[1] = m4.y; me[2] = m4.z; me[3] = m4.w;
    }
    float wnA[HE], wnB[HE];
    {
        const float4 w4 = ((const float4*)(wde_e_g + NE))[t];   // wde_e[1]
        wnA[0] = w4.x; wnA[1] = w4.y; wnA[2] = w4.z; wnA[3] = w4.w;
    }
    float bcA[HE], bcB[HE];
    float tm[HE];
    {
        const float4 bp4 = ((const float4*)base_e_g)[t];   // layer 0
        bcA[0] = bp4.x; bcA[1] = bp4.y; bcA[2] = bp4.z; bcA[3] = bp4.w;
        #pragma unroll
        for (int k = 0; k < HE; ++k) tm[k] = bcA[k];       // msg == 0
    }

    // ---- zero both exchange arrays (padding slots stay 0 forever) ----
    #pragma unroll
    for (int j = 0; j < 6; ++j) {
        ((float4*)s_cW)[j * NT + t] = make_float4(0.f, 0.f, 0.f, 0.f);
        ((float4*)s_cM)[j * NT + t] = make_float4(0.f, 0.f, 0.f, 0.f);
    }

    float loss = 0.0f;
    __syncthreads();

    // ---- layer loop, unrolled x2 with A/B prefetch-buffer swap ----
    for (int l = 0; l < LL; l += 2) {
        LAYER_BODY(l,     wnA, wnB, bcB);
        LAYER_BODY(l + 1, wnB, wnA, bcA);
    }

    // tail: loss for the last layer (degree-gated slot-sum, bit-exact)
    {
        const float rr = rhos[LL - 1];
        float bel0 = bias[0], bel1 = bias[1];
        {
            float4 a = ((const float4*)s_cM)[t];
            float4 c4 = ((const float4*)s_cM)[t + NT];
            bel0 += (a.x + a.y) + (a.z + a.w);
            bel1 += (c4.x + c4.y) + (c4.z + c4.w);
        }
        if (deg0 > 4) {
            float4 a = ((const float4*)s_cM)[NN + t];
            bel0 += (a.x + a.y) + (a.z + a.w);
        }
        if (deg1 > 4) {
            float4 c4 = ((const float4*)s_cM)[NN + t + NT];
            bel1 += (c4.x + c4.y) + (c4.z + c4.w);
        }
        if (deg0 > 8) {
            float4 a = ((const float4*)s_cM)[2 * NN + t];
            bel0 += (a.x + a.y) + (a.z + a.w);
        }
        if (deg1 > 8) {
            float4 c4 = ((const float4*)s_cM)[2 * NN + t + NT];
            bel1 += (c4.x + c4.y) + (c4.z + c4.w);
        }
        float sp0 = fmaxf(bel0, 0.0f) + __logf(1.0f + __expf(-fabsf(bel0)));
        float sp1 = fmaxf(bel1, 0.0f) + __logf(1.0f + __expf(-fabsf(bel1)));
        loss += rr * ((sp0 - omeg[0] * bel0) + (sp1 - omeg[1] * bel1));
    }

    // ---- block-wide loss reduction (12 waves) ----
    #pragma unroll
    for (int off = 32; off > 0; off >>= 1)
        loss += __shfl_down(loss, off, 64);
    int wave = t >> 6, lane = t & 63;
    if (lane == 0) s_red[wave] = loss;
    __syncthreads();
    if (t == 0) {
        float tot = 0.0f;
        #pragma unroll
        for (int w = 0; w < 12; ++w) tot += s_red[w];
        atomicAdd(out, tot * (1.0f / (float)MB));
    }
}

// ---------------------------------------------------------------------------
extern "C" void kernel_launch(void* const* d_in, const int* in_sizes, int n_in,
                              void* d_out, int out_size, void* d_ws, size_t ws_size,
                              hipStream_t stream) {
    const float* synd     = (const float*)d_in[0];
    const float* errors   = (const float*)d_in[1];
    const float* H        = (const float*)d_in[2];
    const float* llrs     = (const float*)d_in[3];
    const float* w_de     = (const float*)d_in[4];
    const float* w_llr    = (const float*)d_in[5];
    const float* marg_de  = (const float*)d_in[6];
    const float* marg_llr = (const float*)d_in[7];
    const float* res_w    = (const float*)d_in[8];
    const float* rhos     = (const float*)d_in[9];
    float* out = (float*)d_out;

    float* wde_e   = (float*)d_ws;
    float* base_e  = wde_e + (size_t)LL * NE;
    float* marg_e  = base_e + (size_t)LL * NE;
    int*   gcnt    = (int*)(marg_e + NE);
    int*   col_pack= (int*)(gcnt + NN);

    hipMemsetAsync(gcnt, 0, NN * sizeof(int), stream);
    setup_kernel<<<MM, 256, 0, stream>>>(H, llrs, w_llr, w_de, marg_de,
                                         col_pack, base_e, wde_e, marg_e,
                                         gcnt, out);
    bp_kernel<<<MB, NT, 0, stream>>>(synd, errors, llrs, marg_llr, res_w, rhos,
                                     col_pack, base_e, wde_e, marg_e, gcnt, out);
}